// Round 15
// baseline (142.713 us; speedup 1.0000x reference)
//
#include <hip/hip_runtime.h>

#define G_    32
#define N_    128
#define NP1_  129
#define H_    32
#define EAD_  16
#define MAXD_ 5
#define NE_   65536
#define NPTH_ 1048576
#define ILP_  8      // mixfold batch factor

// round-to-nearest-even f32 -> bf16 bits
static __device__ __forceinline__ unsigned int f2bf(float f) {
  unsigned int u = __float_as_uint(f);
  u += 0x7fffu + ((u >> 16) & 1u);
  return u >> 16;
}
static __device__ __forceinline__ float bf2f(unsigned int v) {
  return __uint_as_float(v << 16);
}

// ---------------------------------------------------------------------------
// Kernel 0: fast zero-fill (runtime fillBufferAligned measured 0.32 TB/s /
// 8.5% occupancy; this grid-stride uint4 fill streams at ~4TB/s).
// ---------------------------------------------------------------------------
__global__ __launch_bounds__(256) void zero_fill_kernel(
    uint4* __restrict__ dst, int n16) {
  int idx = blockIdx.x * blockDim.x + threadIdx.x;
  int stride = gridDim.x * blockDim.x;
  const uint4 z = make_uint4(0u, 0u, 0u, 0u);
  for (int i = idx; i < n16; i += stride) dst[i] = z;
}

// ---------------------------------------------------------------------------
// Kernel 1: edge encoder -> bf16 eavalb[NE][H] (4MB: per-XCD-L2-resident,
// the whole point of this round) ; edge_map[(g,i,j)] = e+1.
// ---------------------------------------------------------------------------
__global__ __launch_bounds__(256) void edge_encode_kernel(
    const float* __restrict__ edge_attr,    // [NE][16]
    const int*   __restrict__ edge_index,   // [3][NE]
    const float* __restrict__ edge_enc_w,   // [H][16]
    unsigned short* __restrict__ eavalb,    // [NE][H] bf16
    int*         __restrict__ edge_map) {   // [G][N][N], e+1 (0 = empty)
  int t = blockIdx.x * blockDim.x + threadIdx.x;
  if (t >= NE_ * H_) return;
  int e = t >> 5;
  int h = t & 31;
  const float* ea = edge_attr + e * EAD_;
  const float* w  = edge_enc_w + h * EAD_;
  float s = 0.f;
#pragma unroll
  for (int k = 0; k < EAD_; ++k) s += ea[k] * w[k];
  eavalb[t] = (unsigned short)f2bf(s);
  if (h == 0) {
    int g = edge_index[e];
    int i = edge_index[NE_ + e];
    int j = edge_index[2 * NE_ + e];
    edge_map[(g * N_ + i) * N_ + j] = e + 1;
  }
}

// ---------------------------------------------------------------------------
// Kernel 2: destination-organized path scatter. Probe edge_map first; load
// destination components only on hit (12.5%). Sets per-cell flag.
// ---------------------------------------------------------------------------
__global__ __launch_bounds__(256) void path_scatter_kernel(
    const int* __restrict__ path_index,     // [6][NPTH]
    const int* __restrict__ edge_map,       // [G][N][N]
    int*       __restrict__ slot,           // [G*N*N][MAXD]
    unsigned char* __restrict__ flags) {    // [G*N*N]
  int p = blockIdx.x * blockDim.x + threadIdx.x;
  int pg = path_index[p];
  int ps = path_index[4 * NPTH_ + p];
  int pt = path_index[5 * NPTH_ + p];
  int m = edge_map[(pg * N_ + ps) * N_ + pt];
  if (m) {
    int pi = path_index[NPTH_ + p];
    int pj = path_index[2 * NPTH_ + p];
    int pd = path_index[3 * NPTH_ + p];
    int cell = (pg * N_ + pi) * N_ + pj;
    slot[(size_t)cell * MAXD_ + pd] = m;
    flags[cell] = 1;
  }
}

// ---------------------------------------------------------------------------
// Kernel 3: streaming fold with in-register mix. Thread = (cell,h), h=lane;
// 8-way ILP over cells spaced TOT/8 apart. Empty cells (78%): flag->spe->
// store. Hit cells: 5 slot ints + per hit-d one 64B bf16 eavalb row
// (uniform per half-wave, 1-2 lines, L2-resident 4MB) x Wd (20KB, L1)
// -> 32 FMA. No barriers, no LDS, no atomics.
// ---------------------------------------------------------------------------
__global__ __launch_bounds__(256) void mixfold_kernel(
    const int*   __restrict__ slot,         // [G*N*N][MAXD]
    const unsigned char* __restrict__ flags,// [G*N*N]
    const int*   __restrict__ spatial_pos,  // [G*N*N]
    const float* __restrict__ spe,          // [512][H]
    const unsigned short* __restrict__ eavalb, // [NE][H] bf16
    const float* __restrict__ Wdis,         // [d][h][k] f32
    unsigned short* __restrict__ valmid) {  // [G*N*N][H] bf16
  const int TOT   = G_ * N_ * N_ * H_;      // 16.7M
  const int CHUNK = TOT / ILP_;             // 2.10M
  const int CCH   = CHUNK >> 5;             // cells per chunk
  int base = blockIdx.x * blockDim.x + threadIdx.x;   // exact grid = CHUNK
  int h  = base & 31;
  int c0 = base >> 5;

  int cells[ILP_];
#pragma unroll
  for (int k = 0; k < ILP_; ++k) cells[k] = c0 + k * CCH;

  unsigned char fl[ILP_];
  int sv[ILP_];
#pragma unroll
  for (int k = 0; k < ILP_; ++k) fl[k] = flags[cells[k]];  // sequential stream
#pragma unroll
  for (int k = 0; k < ILP_; ++k) sv[k] = spatial_pos[cells[k]];

  float acc[ILP_];
#pragma unroll
  for (int k = 0; k < ILP_; ++k) acc[k] = 0.f;
#pragma unroll
  for (int k = 0; k < ILP_; ++k) {
    if (fl[k]) {                                    // half-wave-uniform
      const int* srow = slot + (size_t)cells[k] * MAXD_;
      int m[MAXD_];
#pragma unroll
      for (int d = 0; d < MAXD_; ++d) m[d] = srow[d];
#pragma unroll
      for (int d = 0; d < MAXD_; ++d) {
        if (m[d]) {
          const unsigned int* er =
              (const unsigned int*)(eavalb + (size_t)(m[d] - 1) * H_);
          const float* Wd = Wdis + d * (H_ * H_);   // L1-resident
          float v0 = 0.f, v1 = 0.f, v2 = 0.f, v3 = 0.f;
#pragma unroll
          for (int hh = 0; hh < H_; hh += 4) {
            unsigned int wa = er[hh >> 1];          // uniform u32 (2 bf16)
            unsigned int wb = er[(hh >> 1) + 1];
            v0 += bf2f(wa & 0xFFFFu) * Wd[(hh + 0) * H_ + h];
            v1 += bf2f(wa >> 16)     * Wd[(hh + 1) * H_ + h];
            v2 += bf2f(wb & 0xFFFFu) * Wd[(hh + 2) * H_ + h];
            v3 += bf2f(wb >> 16)     * Wd[(hh + 3) * H_ + h];
          }
          acc[k] += (v0 + v1) + (v2 + v3);
        }
      }
    }
  }

#pragma unroll
  for (int k = 0; k < ILP_; ++k) {
    int s = sv[k];
    int s2 = (s == 0) ? 1 : s;
    s2 = (s2 > 1) ? s2 - 1 : s2;
    s2 = (s2 > MAXD_) ? MAXD_ : s2;
    float inv = (s2 == 1) ? 1.0f
              : (s2 == 2) ? 0.5f
              : (s2 == 3) ? (1.0f / 3.0f)
              : (s2 == 4) ? 0.25f : 0.2f;
    float val = spe[s * H_ + h] + acc[k] * inv;     // coalesced 128B row
    valmid[base + k * CHUNK] = (unsigned short)f2bf(val);
  }
}

// ---------------------------------------------------------------------------
// Kernel 4: output transpose + assembly (r11-proven). Block per (g, a) row.
// Phase A: uint4 loads of the 8KB bf16 valmid row -> padded LDS.
// Phase B: out[g][h][a][:] = 2*ab + (b==0 ? virt : lds), NT stores.
// ---------------------------------------------------------------------------
__global__ __launch_bounds__(256) void output_kernel(
    const float* __restrict__ attn_bias,      // [G][129][129]
    const float* __restrict__ virt,           // [H]
    const unsigned short* __restrict__ valmid,// [G*N*N][H] bf16
    float* __restrict__ out) {                // [G][H][129][129]
  __shared__ float lds_val[N_ * 33];          // padded transpose tile
  __shared__ float lds_virt[H_];

  int blk = blockIdx.x;
  int g = blk / NP1_;
  int a = blk - g * NP1_;
  int tid = threadIdx.x;

  if (tid < H_) lds_virt[tid] = virt[tid];

  const float* ab = attn_bias + (g * NP1_ + a) * NP1_;

  if (a == 0) {
    __syncthreads();
    for (int t = tid; t < H_ * NP1_; t += 256) {
      int h = t / NP1_;
      int b = t - h * NP1_;
      __builtin_nontemporal_store(
          2.f * ab[b] + lds_virt[h],
          &out[((g * H_ + h) * NP1_) * NP1_ + b]);
    }
    return;
  }

  int i = a - 1;
  const uint4* vrow =
      (const uint4*)(valmid + (size_t)(g * N_ + i) * N_ * H_);  // 8KB row

  // phase A: 512 x 16B loads (8 bf16 each), 2 per thread, unpack to LDS
  for (int u = tid; u < 512; u += 256) {
    uint4 w = vrow[u];
    int base = u * 8;                         // element = j*32 + h
    unsigned int ws[4] = {w.x, w.y, w.z, w.w};
#pragma unroll
    for (int q = 0; q < 4; ++q) {
      int el = base + q * 2;
      int j  = el >> 5;
      int hh = el & 31;                       // even, hh+1 same j
      lds_val[j * 33 + hh]     = __uint_as_float((ws[q] & 0xFFFFu) << 16);
      lds_val[j * 33 + hh + 1] = __uint_as_float(ws[q] & 0xFFFF0000u);
    }
  }
  __syncthreads();

  // phase B: transposed LDS reads (2-way max = free), NT coalesced stores
  for (int t = tid; t < H_ * NP1_; t += 256) {
    int h = t / NP1_;
    int b = t - h * NP1_;
    float val = 2.f * ab[b];
    val += (b == 0) ? lds_virt[h] : lds_val[(b - 1) * 33 + h];
    __builtin_nontemporal_store(
        val, &out[((g * H_ + h) * NP1_ + a) * NP1_ + b]);
  }
}

// ---------------------------------------------------------------------------
extern "C" void kernel_launch(void* const* d_in, const int* in_sizes, int n_in,
                              void* d_out, int out_size, void* d_ws, size_t ws_size,
                              hipStream_t stream) {
  const float* attn_bias   = (const float*)d_in[0];
  const int*   spatial_pos = (const int*)d_in[1];
  const int*   edge_index  = (const int*)d_in[2];
  const float* edge_attr   = (const float*)d_in[3];
  const int*   path_index  = (const int*)d_in[4];
  const float* edge_enc_w  = (const float*)d_in[5];
  const float* spe         = (const float*)d_in[6];
  const float* virt        = (const float*)d_in[7];
  const float* edge_dis    = (const float*)d_in[8];
  float* out = (float*)d_out;

  const size_t SLOT_ELEMS = (size_t)G_ * N_ * N_ * MAXD_;  // 2.62M ints
  const size_t MAP_ELEMS  = (size_t)G_ * N_ * N_;          // 512K ints
  const size_t FLAG_INTS  = (size_t)G_ * N_ * N_ / 4;      // 512KB as ints
  const size_t EAV_SHORTS = (size_t)NE_ * H_;              // 2.1M ushorts, 4MB

  int*            slot     = (int*)d_ws;
  int*            edge_map = slot + SLOT_ELEMS;
  unsigned char*  flags    = (unsigned char*)(edge_map + MAP_ELEMS);
  unsigned short* eavalb   = (unsigned short*)(edge_map + MAP_ELEMS + FLAG_INTS);
  unsigned short* valmid   = eavalb + EAV_SHORTS;          // 33.5MB

  // zero slot + edge_map + flags (13.1MB) with the streaming fill
  {
    int n16 = (int)((SLOT_ELEMS + MAP_ELEMS + FLAG_INTS) * sizeof(int) / 16);
    zero_fill_kernel<<<1024, 256, 0, stream>>>((uint4*)d_ws, n16);
  }

  // edge encoder (bf16) + map
  edge_encode_kernel<<<(NE_ * H_ + 255) / 256, 256, 0, stream>>>(
      edge_attr, edge_index, edge_enc_w, eavalb, edge_map);
  // destination-organized path scatter (+ flags, conditional tails)
  path_scatter_kernel<<<NPTH_ / 256, 256, 0, stream>>>(
      path_index, edge_map, slot, flags);
  // streaming fold with in-register mix (L2-resident eavalb)
  mixfold_kernel<<<(G_ * N_ * N_ * H_ / ILP_) / 256, 256, 0, stream>>>(
      slot, flags, spatial_pos, spe, eavalb, edge_dis, valmid);
  // output transpose + assembly
  output_kernel<<<G_ * NP1_, 256, 0, stream>>>(
      attn_bias, virt, valmid, out);
}